// Round 3
// baseline (300.864 us; speedup 1.0000x reference)
//
#include <hip/hip_runtime.h>

// x        [64, 524288] f32 | idx_feat [4096,256] f32 | weight [64,256] f32
// bias     [64] f32         | pred_cate [4096] i32    | pred_score [4096] f32
// out (f32 concat): seg_pred [53*524288], unique_cate [53], fused_score [53]

#define KK   4096
#define CIN  256
#define CC   64
#define HW   524288   // 512*1024
#define HW2  (HW / 2) // float2 columns
#define UU   53
#define FWS  56       // fwt row stride (53 padded)

// ws layout (floats) — only fwt; no atomics, no memset needed
#define WS_FWT 0      // fw TRANSPOSED [64][FWS]

typedef float f2 __attribute__((ext_vector_type(2)));

// ---------------------------------------------------------------------------
// Fused stages 1+2 (UNCHANGED from round 2): one block per class u.
// ---------------------------------------------------------------------------
__global__ __launch_bounds__(256)
void fused12_kernel(const float* __restrict__ idx_feat,
                    const int*   __restrict__ pred_cate,
                    const float* __restrict__ pred_score,
                    const float* __restrict__ weight,
                    const float* __restrict__ bias,
                    float* __restrict__ ws,
                    float* __restrict__ out)
{
    const int u   = blockIdx.x;
    const int tid = threadIdx.x;

    __shared__ int   list[128];    // max count per class is 78 (4096 = 53*77+15)
    __shared__ int   nmatch;
    __shared__ float sumf[CIN];    // per-cin class feature sums
    __shared__ float wsum[4];      // per-wave score partials

    if (tid == 0) nmatch = 0;
    __syncthreads();

    // ---- Phase A: scan + compact + score ----
    float sc = 0.0f;
    #pragma unroll
    for (int k = tid; k < KK; k += 256) {       // coalesced int loads
        if (pred_cate[k] == u) {
            int pos = atomicAdd(&nmatch, 1);    // LDS atomic, ~77/block total
            list[pos] = k;
            sc += pred_score[k];
        }
    }
    // wave-reduce score (64 lanes)
    #pragma unroll
    for (int off = 32; off > 0; off >>= 1) sc += __shfl_down(sc, off);
    if ((tid & 63) == 0) wsum[tid >> 6] = sc;
    __syncthreads();                            // list + wsum complete

    // ---- Phase B: feature sums, thread owns cin = tid ----
    const int n = nmatch;                       // uniform
    float acc = 0.0f;
    #pragma unroll 4
    for (int m = 0; m < n; ++m) {
        const int k = list[m];                  // uniform LDS broadcast
        acc += idx_feat[(size_t)k * CIN + tid]; // coalesced row load
    }
    sumf[tid] = acc;
    __syncthreads();

    // ---- Phase C: fw[:,u] = (weight @ mean_u) + bias, transposed store ----
    const float inv = 1.0f / (float)n;
    const int c = tid >> 2;                     // output channel 0..63
    const int q = tid & 3;                      // quarter of the 256-dot
    float d = 0.0f;
    const int i0 = q * 64;
    #pragma unroll 8
    for (int i = 0; i < 64; ++i)
        d = fmaf(sumf[i0 + i], weight[(size_t)c * CIN + i0 + i], d);
    d += __shfl_xor(d, 1);
    d += __shfl_xor(d, 2);                      // q-group of 4 summed
    if (q == 0)
        ws[WS_FWT + c * FWS + u] = d * inv + bias[c];

    if (tid == 0) {
        out[(size_t)UU * HW + u]      = (float)u;                       // unique_cate
        out[(size_t)UU * HW + UU + u] = (wsum[0] + wsum[1] + wsum[2] + wsum[3]) * inv; // fused_score
    }
}

// ---------------------------------------------------------------------------
// Stage 3: seg_pred = fw [53,64] @ x [64, HW].
// CHANGED this round: thread owns one float2 column (was float4).
//  - acc: 53 f2 = 106 VGPR (was 212) -> __launch_bounds__(256,3) = 12
//    waves/CU (was 8), no spill risk.
//  - grid 1024 blocks (was 512); #pragma unroll 4 -> 4 nt loads in flight
//    per thread; in-flight/CU ~ 24 KB vs ~10 KB needed to cover ~900 cyc
//    HBM latency at ~11 B/cyc/CU.
//  - per-column accumulation order identical -> bit-identical output.
// Floors unchanged: mem 245 MB @ ~6.7 TB/s = 37 us; VALU 22.6 us.
// ---------------------------------------------------------------------------
__global__ __launch_bounds__(256, 3)
void seg_pred_kernel(const float* __restrict__ x,
                     const float* __restrict__ ws,
                     float* __restrict__ out)
{
    const int j = blockIdx.x * 256 + threadIdx.x;   // float2 column index
    const f2* x2   = (const f2*)x;
    f2*       out2 = (f2*)out;
    const float* fwt = ws + WS_FWT;

    f2 acc[UU];
    #pragma unroll
    for (int u = 0; u < UU; ++u) acc[u] = (f2)0.0f;

    #pragma unroll 4
    for (int c = 0; c < CC; ++c) {
        const f2 xv = __builtin_nontemporal_load(&x2[(size_t)c * HW2 + j]);
        #pragma unroll
        for (int u = 0; u < UU; ++u) {
            const float w = fwt[c * FWS + u];        // uniform, consecutive
            acc[u].x = fmaf(w, xv.x, acc[u].x);
            acc[u].y = fmaf(w, xv.y, acc[u].y);
        }
    }

    #pragma unroll
    for (int u = 0; u < UU; ++u)
        __builtin_nontemporal_store(acc[u], &out2[(size_t)u * HW2 + j]);
}

extern "C" void kernel_launch(void* const* d_in, const int* in_sizes, int n_in,
                              void* d_out, int out_size, void* d_ws, size_t ws_size,
                              hipStream_t stream)
{
    const float* x          = (const float*)d_in[0];
    const float* idx_feat   = (const float*)d_in[1];
    const float* weight     = (const float*)d_in[2];
    const float* bias       = (const float*)d_in[3];
    const int*   pred_cate  = (const int*)d_in[4];
    const float* pred_score = (const float*)d_in[5];

    float* out = (float*)d_out;
    float* ws  = (float*)d_ws;

    fused12_kernel<<<UU, 256, 0, stream>>>(idx_feat, pred_cate, pred_score,
                                           weight, bias, ws, out);
    seg_pred_kernel<<<HW2 / 256, 256, 0, stream>>>(x, ws, out);  // 1024 blocks
}